// Round 1
// baseline (524.497 us; speedup 1.0000x reference)
//
#include <hip/hip_runtime.h>

#define NS 131072
#define INDIM 128
#define LDIM 16
#define KC 8
#define DD 50
#define EH 64
#define DH 16
#define HH 64

typedef unsigned long long u64;

// ---------------------------------------------------------------------------
// Kernel A: fused encoder -> z -> student-t q/argmax -> decoder -> x_hat/rec
// One thread per sample. Weights via uniform (scalar) loads. Activations are
// round-tripped through LDS in 16-row chunks so inner loops never need
// runtime register indexing.
// ---------------------------------------------------------------------------
__global__ __launch_bounds__(256) void k_enc(
    const float* __restrict__ x,
    const float* __restrict__ We1, const float* __restrict__ be1,
    const float* __restrict__ We2, const float* __restrict__ be2,
    const float* __restrict__ We3, const float* __restrict__ be3,
    const float* __restrict__ Wd1, const float* __restrict__ bd1,
    const float* __restrict__ Wd2, const float* __restrict__ bd2,
    const float* __restrict__ centers,
    float* __restrict__ out,
    int* __restrict__ cidx, int* __restrict__ counts)
{
    const int t = threadIdx.x;
    const int s = blockIdx.x * 256 + t;
    __shared__ float buf[16][257];

    const float4* x4 = reinterpret_cast<const float4*>(x + (size_t)s * INDIM);

    // ---------------- layer 1: e1 = relu(x @ We1 + be1) ----------------
    float a1[EH];
    #pragma unroll
    for (int j = 0; j < EH; ++j) a1[j] = be1[j];
    for (int fc = 0; fc < INDIM / 4; ++fc) {
        float4 v = x4[fc];
        float xr[4] = {v.x, v.y, v.z, v.w};
        #pragma unroll
        for (int fl = 0; fl < 4; ++fl) {
            const float* w = We1 + (fc * 4 + fl) * EH;
            #pragma unroll
            for (int j = 0; j < EH; ++j) a1[j] = fmaf(xr[fl], w[j], a1[j]);
        }
    }
    #pragma unroll
    for (int j = 0; j < EH; ++j) a1[j] = fmaxf(a1[j], 0.0f);

    // ---------------- layer 2: e2 = relu(e1 @ We2 + be2) ----------------
    float a2[EH];
    #pragma unroll
    for (int j = 0; j < EH; ++j) a2[j] = be2[j];
    for (int hc = 0; hc < 4; ++hc) {
        #pragma unroll
        for (int hl = 0; hl < 16; ++hl) buf[hl][t] = a1[hc * 16 + hl];
        __syncthreads();
        for (int hl = 0; hl < 16; ++hl) {
            float ev = buf[hl][t];
            const float* w = We2 + (hc * 16 + hl) * EH;
            #pragma unroll
            for (int j = 0; j < EH; ++j) a2[j] = fmaf(ev, w[j], a2[j]);
        }
        __syncthreads();
    }
    #pragma unroll
    for (int j = 0; j < EH; ++j) a2[j] = fmaxf(a2[j], 0.0f);

    // ---------------- layer 3: z = e2 @ We3 + be3 (no relu) ----------------
    float z[LDIM];
    #pragma unroll
    for (int j = 0; j < LDIM; ++j) z[j] = be3[j];
    for (int hc = 0; hc < 4; ++hc) {
        #pragma unroll
        for (int hl = 0; hl < 16; ++hl) buf[hl][t] = a2[hc * 16 + hl];
        __syncthreads();
        for (int hl = 0; hl < 16; ++hl) {
            float ev = buf[hl][t];
            const float* w = We3 + (hc * 16 + hl) * LDIM;
            #pragma unroll
            for (int j = 0; j < LDIM; ++j) z[j] = fmaf(ev, w[j], z[j]);
        }
        __syncthreads();
    }

    // write z
    {
        float4* oz = reinterpret_cast<float4*>(out + (size_t)s * LDIM);
        oz[0] = make_float4(z[0], z[1], z[2], z[3]);
        oz[1] = make_float4(z[4], z[5], z[6], z[7]);
        oz[2] = make_float4(z[8], z[9], z[10], z[11]);
        oz[3] = make_float4(z[12], z[13], z[14], z[15]);
    }

    // ---------------- student-t similarity + softmax + argmax ----------------
    float d2[KC];
    #pragma unroll
    for (int k = 0; k < KC; ++k) {
        float acc = 0.0f;
        #pragma unroll
        for (int l = 0; l < LDIM; ++l) {
            float dl = z[l] - centers[k * LDIM + l];
            acc = fmaf(dl, dl, acc);
        }
        d2[k] = acc;
    }
    float lgt[KC];
    #pragma unroll
    for (int k = 0; k < KC; ++k) lgt[k] = -log1pf(d2[k]);   // -0.5*(df+1)*log1p(d2/df), df=1
    float m = lgt[0];
    #pragma unroll
    for (int k = 1; k < KC; ++k) m = fmaxf(m, lgt[k]);
    float ex[KC];
    float ssum = 0.0f;
    #pragma unroll
    for (int k = 0; k < KC; ++k) { ex[k] = expf(lgt[k] - m); ssum += ex[k]; }
    {
        float q[KC];
        #pragma unroll
        for (int k = 0; k < KC; ++k) q[k] = ex[k] / ssum;
        float4* oq = reinterpret_cast<float4*>(out + (size_t)NS * LDIM + (size_t)s * KC);
        oq[0] = make_float4(q[0], q[1], q[2], q[3]);
        oq[1] = make_float4(q[4], q[5], q[6], q[7]);
    }
    // argmax(q) == argmin(dist2); first-wins on ties (strict <) matches jnp.argmax
    int ci = 0;
    float best = d2[0];
    #pragma unroll
    for (int k = 1; k < KC; ++k) if (d2[k] < best) { best = d2[k]; ci = k; }
    cidx[s] = ci;

    // per-wave histogram (ballot-aggregated -> 8 atomics per wave)
    #pragma unroll
    for (int k = 0; k < KC; ++k) {
        u64 mk = __ballot(ci == k);
        if ((t & 63) == 0 && mk) atomicAdd(&counts[k], (int)__popcll(mk));
    }

    // ---------------- decoder: d = relu(z @ Wd1 + bd1); x_hat = d @ Wd2 + bd2
    float dh[DH];
    #pragma unroll
    for (int j = 0; j < DH; ++j) dh[j] = bd1[j];
    #pragma unroll
    for (int h = 0; h < LDIM; ++h) {
        float zv = z[h];
        #pragma unroll
        for (int j = 0; j < DH; ++j) dh[j] = fmaf(zv, Wd1[h * DH + j], dh[j]);
    }
    #pragma unroll
    for (int j = 0; j < DH; ++j) dh[j] = fmaxf(dh[j], 0.0f);

    float rec = 0.0f;
    float* oxh = out + (size_t)NS * 74 + (size_t)s * INDIM;
    for (int jc = 0; jc < 8; ++jc) {
        float xh[16];
        #pragma unroll
        for (int j = 0; j < 16; ++j) xh[j] = bd2[jc * 16 + j];
        #pragma unroll
        for (int h = 0; h < DH; ++h) {
            float dv = dh[h];
            #pragma unroll
            for (int j = 0; j < 16; ++j)
                xh[j] = fmaf(dv, Wd2[h * INDIM + jc * 16 + j], xh[j]);
        }
        float4 xa = x4[jc * 4 + 0], xb = x4[jc * 4 + 1];
        float4 xc = x4[jc * 4 + 2], xd = x4[jc * 4 + 3];
        float xs[16] = {xa.x, xa.y, xa.z, xa.w, xb.x, xb.y, xb.z, xb.w,
                        xc.x, xc.y, xc.z, xc.w, xd.x, xd.y, xd.z, xd.w};
        #pragma unroll
        for (int j = 0; j < 16; ++j) {
            float df_ = xh[j] - xs[j];
            rec = fmaf(df_, df_, rec);
        }
        float4* o4 = reinterpret_cast<float4*>(oxh + jc * 16);
        o4[0] = make_float4(xh[0], xh[1], xh[2], xh[3]);
        o4[1] = make_float4(xh[4], xh[5], xh[6], xh[7]);
        o4[2] = make_float4(xh[8], xh[9], xh[10], xh[11]);
        o4[3] = make_float4(xh[12], xh[13], xh[14], xh[15]);
    }
    out[(size_t)NS * 202 + s] = rec * (1.0f / 128.0f);   // mean over 128 (exact pow2)
    out[(size_t)NS * 203 + s] = 0.0f;                    // kld
}

// ---------------------------------------------------------------------------
// Kernel B: exclusive scan of K=8 counts -> bases, cursors
// ---------------------------------------------------------------------------
__global__ void k_scan(const int* __restrict__ counts,
                       int* __restrict__ bases, int* __restrict__ cursors)
{
    if (threadIdx.x == 0) {
        int acc = 0;
        for (int k = 0; k < KC; ++k) {
            bases[k] = acc;
            cursors[k] = acc;
            acc += counts[k];
        }
    }
}

// ---------------------------------------------------------------------------
// Kernel C: counting-sort scatter of sample ids into per-cluster segments.
// Ballot-aggregated: one atomic per (wave, cluster).
// ---------------------------------------------------------------------------
__global__ __launch_bounds__(256) void k_scatter(
    const int* __restrict__ cidx, int* __restrict__ cursors, int* __restrict__ seg)
{
    const int s = blockIdx.x * 256 + threadIdx.x;
    const int lane = threadIdx.x & 63;
    const int ci = cidx[s];
    #pragma unroll
    for (int k = 0; k < KC; ++k) {
        u64 mk = __ballot(ci == k);
        if (ci == k) {
            const int leader = __ffsll(mk) - 1;
            int base = 0;
            if (lane == leader) base = atomicAdd(&cursors[k], (int)__popcll(mk));
            base = __shfl(base, leader, 64);
            const int pos = base + (int)__popcll(mk & (((u64)1 << lane) - 1));
            seg[pos] = s;
        }
    }
}

// ---------------------------------------------------------------------------
// Kernel D: routed survival heads. One block = (cluster k, chunk of 256
// samples of that cluster); k is block-uniform so all weight loads are
// uniform (scalar). Only the argmax head is computed per sample.
// ---------------------------------------------------------------------------
__global__ __launch_bounds__(256) void k_heads(
    const float* __restrict__ x, const float* __restrict__ zread,
    const float* __restrict__ Wh1, const float* __restrict__ bh1,
    const float* __restrict__ Wh2, const float* __restrict__ bh2,
    const int* __restrict__ counts, const int* __restrict__ bases,
    const int* __restrict__ seg,
    float* __restrict__ surv)
{
    __shared__ float buf[16][257];
    const int b = blockIdx.x;
    int k = -1, chunk = 0, pref = 0;
    #pragma unroll
    for (int kk = 0; kk < KC; ++kk) {
        int ck = (counts[kk] + 255) >> 8;
        if (k < 0) {
            if (b < pref + ck) { k = kk; chunk = b - pref; }
            pref += ck;
        }
    }
    if (k < 0) return;                 // uniform per block: barrier-safe
    const int cnt = counts[k];
    const int t = threadIdx.x;
    const int i = chunk * 256 + t;
    const bool act = i < cnt;
    const int idx = act ? seg[bases[k] + i] : 0;

    // h = [z, x] ; h1 = relu(h @ Wh1[k] + bh1[k])
    float a[HH];
    #pragma unroll
    for (int j = 0; j < HH; ++j) a[j] = bh1[k * HH + j];

    const float4* z4 = reinterpret_cast<const float4*>(zread + (size_t)idx * LDIM);
    for (int fc = 0; fc < 4; ++fc) {
        float4 v = z4[fc];
        float r[4] = {v.x, v.y, v.z, v.w};
        #pragma unroll
        for (int fl = 0; fl < 4; ++fl) {
            const float* w = Wh1 + ((size_t)k * 144 + fc * 4 + fl) * HH;
            #pragma unroll
            for (int j = 0; j < HH; ++j) a[j] = fmaf(r[fl], w[j], a[j]);
        }
    }
    const float4* xx4 = reinterpret_cast<const float4*>(x + (size_t)idx * INDIM);
    for (int fc = 0; fc < 32; ++fc) {
        float4 v = xx4[fc];
        float r[4] = {v.x, v.y, v.z, v.w};
        #pragma unroll
        for (int fl = 0; fl < 4; ++fl) {
            const float* w = Wh1 + ((size_t)k * 144 + 16 + fc * 4 + fl) * HH;
            #pragma unroll
            for (int j = 0; j < HH; ++j) a[j] = fmaf(r[fl], w[j], a[j]);
        }
    }
    #pragma unroll
    for (int j = 0; j < HH; ++j) a[j] = fmaxf(a[j], 0.0f);

    // lg = h1 @ Wh2[k] + bh2[k]
    float lg[DD];
    #pragma unroll
    for (int j = 0; j < DD; ++j) lg[j] = bh2[k * DD + j];
    for (int hc = 0; hc < 4; ++hc) {
        #pragma unroll
        for (int hl = 0; hl < 16; ++hl) buf[hl][t] = a[hc * 16 + hl];
        __syncthreads();
        for (int hl = 0; hl < 16; ++hl) {
            float hv = buf[hl][t];
            const float* w = Wh2 + ((size_t)k * HH + hc * 16 + hl) * DD;
            #pragma unroll
            for (int j = 0; j < DD; ++j) lg[j] = fmaf(hv, w[j], lg[j]);
        }
        __syncthreads();
    }
    if (act) {
        float2* srow = reinterpret_cast<float2*>(surv + (size_t)idx * DD); // 8B aligned
        #pragma unroll
        for (int j = 0; j < DD / 2; ++j) srow[j] = make_float2(lg[2 * j], lg[2 * j + 1]);
    }
}

// ---------------------------------------------------------------------------
extern "C" void kernel_launch(void* const* d_in, const int* in_sizes, int n_in,
                              void* d_out, int out_size, void* d_ws, size_t ws_size,
                              hipStream_t stream)
{
    const float* x   = (const float*)d_in[0];
    const float* We1 = (const float*)d_in[1];
    const float* be1 = (const float*)d_in[2];
    const float* We2 = (const float*)d_in[3];
    const float* be2 = (const float*)d_in[4];
    const float* We3 = (const float*)d_in[5];
    const float* be3 = (const float*)d_in[6];
    const float* Wd1 = (const float*)d_in[7];
    const float* bd1 = (const float*)d_in[8];
    const float* Wd2 = (const float*)d_in[9];
    const float* bd2 = (const float*)d_in[10];
    const float* Wh1 = (const float*)d_in[11];
    const float* bh1 = (const float*)d_in[12];
    const float* Wh2 = (const float*)d_in[13];
    const float* bh2 = (const float*)d_in[14];
    const float* cen = (const float*)d_in[15];
    float* out = (float*)d_out;

    int* cidx    = (int*)d_ws;       // [NS]
    int* counts  = cidx + NS;        // [8]
    int* bases   = counts + KC;      // [8]
    int* cursors = bases + KC;       // [8]
    int* seg     = cursors + KC;     // [NS]

    hipMemsetAsync(counts, 0, KC * sizeof(int), stream);

    k_enc<<<dim3(NS / 256), dim3(256), 0, stream>>>(
        x, We1, be1, We2, be2, We3, be3, Wd1, bd1, Wd2, bd2, cen,
        out, cidx, counts);

    k_scan<<<dim3(1), dim3(64), 0, stream>>>(counts, bases, cursors);

    k_scatter<<<dim3(NS / 256), dim3(256), 0, stream>>>(cidx, cursors, seg);

    k_heads<<<dim3(NS / 256 + KC), dim3(256), 0, stream>>>(
        x, out /* z at offset 0 */, Wh1, bh1, Wh2, bh2,
        counts, bases, seg, out + (size_t)NS * 24 /* surv */);
}